// Round 6
// baseline (342.040 us; speedup 1.0000x reference)
//
#include <hip/hip_runtime.h>
#include <cmath>
#include <climits>

// Fixed problem shape (from setup_inputs)
#define L_    8
#define B_    4
#define T_    2048
#define D_    1024
#define TTL_  1024
#define KSLOT 512          // max events per batch (k=410 total, so safe)
#define TCC   32           // t-chunk (no halo)
#define NCC   (T_/TCC)     // 64
#define ES2   32           // event-split for excess kernel
#define SCH2  32           // s-split for score kernel
#define TIEMAX 256

__device__ __forceinline__ int waveRed(int v){
  for(int o=32;o>0;o>>=1) v += __shfl_xor(v,o,64);
  return v;
}

// ---------------------------------------------------------------------------
// Kernel A: zero accumulators, top-k selection (2-bit radix, exact
// jax.lax.top_k tie-breaking), per-batch sorted event lists (te and
// tend=te+c), flat event arrays, weight w[s]. One block, 1024 threads.
// ---------------------------------------------------------------------------
__global__ __launch_bounds__(1024) void kA(
    const float* __restrict__ pressure, const int* __restrict__ hptr,
    int k, int* __restrict__ evT, int* __restrict__ evE,
    int* __restrict__ evTe, int* __restrict__ evB,
    int* __restrict__ meta, float* __restrict__ w,
    float4* __restrict__ zeroRegion /* S_all..Sscore, 32768 floats */)
{
  {
    float4 z = {0,0,0,0};
    #pragma unroll
    for(int j=0;j<8;++j) zeroRegion[threadIdx.x + j*1024] = z;
  }

  __shared__ unsigned ku[B_*T_];
  __shared__ short ef[B_*T_];
  __shared__ int csum[1024];
  __shared__ int cnt4[4][4];
  __shared__ int scnt;
  __shared__ int s_n[B_];
  __shared__ int s_off[B_];
  __shared__ int tieIdx[TIEMAX];
  __shared__ int tieCnt;
  const int tid = threadIdx.x;
  const int total = B_*T_;
  const int H = hptr[0];

  for(int i=tid;i<total;i+=1024){
    union{float f;unsigned u;} v; v.f = pressure[i];
    unsigned u = v.u;
    ku[i] = (u & 0x80000000u) ? ~u : (u | 0x80000000u);  // monotonic key
  }
  if(tid < B_) s_n[tid] = 0;
  if(tid == 0) tieCnt = 0;
  if(tid < 8) ((int*)cnt4)[tid] = 0;
  __syncthreads();

  // 2-bit radix k-th-largest: 16 iterations, 1 barrier each.
  unsigned p = 0;
  for(int it=0; it<16; ++it){
    const int bit = 30 - 2*it;
    int* A = cnt4[it&3];
    const unsigned q1 = p | (1u<<bit);
    const unsigned q2 = p | (2u<<bit);
    const unsigned q3 = p | (3u<<bit);
    int c1=0,c2=0,c3=0;
    for(int i=tid;i<total;i+=1024){
      unsigned x = ku[i];
      c1 += (x>=q1); c2 += (x>=q2); c3 += (x>=q3);
    }
    c1=waveRed(c1); c2=waveRed(c2); c3=waveRed(c3);
    if((tid&63)==0){ atomicAdd(&A[1],c1); atomicAdd(&A[2],c2); atomicAdd(&A[3],c3); }
    if(tid<4) cnt4[(it+2)&3][tid] = 0;
    __syncthreads();
    const int n1=A[1], n2=A[2], n3=A[3];
    if(n3>=k) p=q3; else if(n2>=k) p=q2; else if(n1>=k) p=q1;
  }
  __syncthreads();
  if(tid==0) scnt=0;
  __syncthreads();
  {
    int c=0;
    for(int i=tid;i<total;i+=1024) c += (ku[i] > p) ? 1 : 0;
    c = waveRed(c);
    if((tid&63)==0) atomicAdd(&scnt, c);
  }
  for(int i=tid;i<total;i+=1024){
    if(ku[i]==p){ int pos=atomicAdd(&tieCnt,1); if(pos<TIEMAX) tieIdx[pos]=i; }
  }
  __syncthreads();
  const int needed = k - scnt;

  for(int j=0;j<8;++j){
    int i = tid*8+j;
    ef[i] = (ku[i] > p) ? (short)1 : (short)0;
  }
  __syncthreads();

  if(tieCnt <= TIEMAX){
    if(tid==0){
      int cnt = tieCnt;
      for(int sel=0; sel<needed; ++sel){
        int best=INT_MAX, bi=-1;
        for(int q=0;q<cnt;++q){ int vv=tieIdx[q]; if(vv>=0 && vv<best){best=vv;bi=q;} }
        if(bi>=0){ tieIdx[bi]=-1; ef[best]=1; }
      }
    }
  } else {
    for(int j=0;j<8;++j){
      int i = tid*8+j;
      if(ku[i]==p){
        int r=0;
        for(int q=0;q<i;++q) r += (ku[q]==p) ? 1 : 0;
        if(r < needed) ef[i]=1;
      }
    }
  }
  __syncthreads();

  {
    int local=0;
    for(int j=0;j<8;++j) local += ef[tid*8+j];
    csum[tid]=local;
  }
  __syncthreads();

  // per-batch sorted event lists (skip te == T-1: fe there is 0)
  for(int j=0;j<8;++j){
    int i = tid*8+j;
    if(ef[i]){
      int b = i / T_, t = i % T_;
      if(t != T_-1){
        int m = 0;
        int ch = i>>3;
        for(int q=(b*T_)>>3; q<ch; ++q) m += csum[q];
        for(int q=ch<<3; q<i; ++q) m += ef[q];
        int c = T_-1-t; if(c>H) c=H;
        evT[b*KSLOT + m] = t;
        evE[b*KSLOT + m] = t + c;
        atomicAdd(&s_n[b], 1);
      }
    }
  }
  __syncthreads();
  if(tid==0){
    int off=0;
    for(int b=0;b<B_;++b){ meta[b]=s_n[b]; meta[4+b]=off; s_off[b]=off; off += s_n[b]; }
    meta[8] = off;  // total listed events
  }
  __syncthreads();
  // flat arrays: global event index e = s_off[b]+j
  for(int i=tid;i<B_*KSLOT;i+=1024){
    int b = i>>9, j = i&511;
    if(j < s_n[b]){ evTe[s_off[b]+j] = evT[i]; evB[s_off[b]+j] = b; }
  }

  // w[s] = sum_{t'=max(0,s-H)}^{s-1} 1/min(H, T-1-t')
  for(int s=tid;s<T_;s+=1024){
    float acc = 0.f;
    int lo = s - H; if(lo < 0) lo = 0;
    for(int t2=lo; t2<s; ++t2){
      int c2 = T_-1-t2; if(c2 > H) c2 = H;
      acc += 1.0f / (float)c2;
    }
    w[s] = acc;
  }
}

// ---------------------------------------------------------------------------
// Kernel B: streaming pass, NO halo. Per (l,b,chunk of 32 rows):
// chunk-local prefix R; writes chunkSum (R at chunk end), ckptS[e]=R(te),
// ckptE[e]=R(te+c) (chunk-local), and accumulates S_all (weighted sq).
// Grid 2048 blocks x 256 thr (float4/thread = full row) -> ~24-32 waves/CU.
// ---------------------------------------------------------------------------
#define LD4(buf, bi) { _Pragma("unroll") for(int j=0;j<4;++j){ \
    buf[j] = sp[(size_t)(t0+(bi)*4+j)*256]; } }

#define CP4(buf, bi) { const int tb = t0+(bi)*4; \
  const bool hm = (nextS < tb+4) || (nextE < tb+4); \
  if(!hm){ _Pragma("unroll") for(int j=0;j<4;++j){ \
      float4 x=buf[j]; \
      float sx=x.x*x.x, sy=x.y*x.y, sz=x.z*x.z, sw=x.w*x.w; \
      R.x+=sx;R.y+=sy;R.z+=sz;R.w+=sw; \
      const float wv = wloc[(bi)*4+j]; \
      A.x=fmaf(wv,sx,A.x);A.y=fmaf(wv,sy,A.y); \
      A.z=fmaf(wv,sz,A.z);A.w=fmaf(wv,sw,A.w); } \
  } else { _Pragma("unroll") for(int j=0;j<4;++j){ \
      float4 x=buf[j]; \
      float sx=x.x*x.x, sy=x.y*x.y, sz=x.z*x.z, sw=x.w*x.w; \
      R.x+=sx;R.y+=sy;R.z+=sz;R.w+=sw; \
      const float wv = wloc[(bi)*4+j]; \
      A.x=fmaf(wv,sx,A.x);A.y=fmaf(wv,sy,A.y); \
      A.z=fmaf(wv,sz,A.z);A.w=fmaf(wv,sw,A.w); \
      const int t = tb+j; \
      if(t == nextS){ \
        float4* cp = (float4*)(ckptS + ((size_t)l*KSLOT + off + m0s + i0)*D_) + tid; \
        *cp = R; ++i0; nextS = (i0<nS) ? sTe[m0s+i0] : INT_MAX; } \
      while(t == nextE){ \
        float4* cp = (float4*)(ckptE + ((size_t)l*KSLOT + off + m0e + i1)*D_) + tid; \
        *cp = R; ++i1; nextE = (i1<nE) ? sEn[m0e+i1] : INT_MAX; } } } }

__global__ __launch_bounds__(256) void kB(
    const float* __restrict__ states, const float* __restrict__ w,
    const int* __restrict__ evT, const int* __restrict__ evE,
    const int* __restrict__ meta,
    float* __restrict__ S_all, float* __restrict__ chunkSum,
    float* __restrict__ ckptS, float* __restrict__ ckptE)
{
  int bx = blockIdx.x;
  const int ch = bx % NCC; bx /= NCC;
  const int b = bx % B_;  const int l = bx / B_;
  const int tid = threadIdx.x;
  const int t0 = ch*TCC, t1 = t0+TCC;

  __shared__ float wloc[TCC];
  __shared__ int sTe[KSLOT];
  __shared__ int sEn[KSLOT];
  __shared__ int cnts[4];

  const int n = meta[b], off = meta[4+b];
  if(tid < TCC) wloc[tid] = w[t0+tid];
  if(tid < 4) cnts[tid] = 0;
  for(int i=tid;i<n;i+=256){ sTe[i]=evT[b*KSLOT+i]; sEn[i]=evE[b*KSLOT+i]; }
  __syncthreads();
  {
    int c0=0,c1=0,c2=0,c3=0;
    for(int i=tid;i<n;i+=256){
      int te=sTe[i], en=sEn[i];
      c0+=(te<t0); c1+=(te<t1); c2+=(en<t0); c3+=(en<t1);
    }
    c0=waveRed(c0); c1=waveRed(c1); c2=waveRed(c2); c3=waveRed(c3);
    if((tid&63)==0){ atomicAdd(&cnts[0],c0); atomicAdd(&cnts[1],c1);
                     atomicAdd(&cnts[2],c2); atomicAdd(&cnts[3],c3); }
  }
  __syncthreads();
  const int m0s=cnts[0], nS=cnts[1]-cnts[0];
  const int m0e=cnts[2], nE=cnts[3]-cnts[2];
  int i0=0, i1=0;
  int nextS = (nS>0) ? sTe[m0s] : INT_MAX;
  int nextE = (nE>0) ? sEn[m0e] : INT_MAX;

  const float4* sp = (const float4*)(states + ((size_t)(l*B_+b)*T_)*D_) + tid;
  float4 R={0,0,0,0}, A={0,0,0,0};
  float4 Ba[4], Bb[4];

  LD4(Ba,0); LD4(Bb,1);
  CP4(Ba,0); LD4(Ba,2);
  CP4(Bb,1); LD4(Bb,3);
  CP4(Ba,2); LD4(Ba,4);
  CP4(Bb,3); LD4(Bb,5);
  CP4(Ba,4); LD4(Ba,6);
  CP4(Bb,5); LD4(Bb,7);
  CP4(Ba,6);
  CP4(Bb,7);

  // chunk totals + weighted accumulation
  float4* csp = (float4*)(chunkSum + (((size_t)(l*B_+b)*NCC)+ch)*D_) + tid;
  *csp = R;
  float* sa = S_all + l*D_ + tid*4;
  atomicAdd(sa+0, A.x); atomicAdd(sa+1, A.y);
  atomicAdd(sa+2, A.z); atomicAdd(sa+3, A.w);
}

// ---------------------------------------------------------------------------
// Kernel P: exclusive scan of chunkSum over the 64 chunks per (l,b,d).
// Grid L_*B_*4 blocks x 64 threads (thread = one float4 lane).
// ---------------------------------------------------------------------------
__global__ __launch_bounds__(64) void kP(
    const float4* __restrict__ cs4, float4* __restrict__ off4)
{
  const int q = blockIdx.x % 4; const int lb = blockIdx.x / 4;
  const int d4 = q*64 + threadIdx.x;   // 0..255
  float4 acc = {0,0,0,0};
  const size_t base = (size_t)lb*NCC*256 + d4;
  #pragma unroll 4
  for(int c=0;c<NCC;++c){
    float4 v = cs4[base + (size_t)c*256];
    off4[base + (size_t)c*256] = acc;
    acc.x+=v.x; acc.y+=v.y; acc.z+=v.z; acc.w+=v.w;
  }
}

// ---------------------------------------------------------------------------
// Kernel F: finalize event fe = ((off[ce]-off[cs]) + (Re-Rs)) / c,
// store into ckptS (in place), accumulate S_ev. Grid L_*KSLOT x 256.
// ---------------------------------------------------------------------------
__global__ __launch_bounds__(256) void kF(
    const float* __restrict__ ckptE, float* __restrict__ ckptS,
    const float* __restrict__ off, const int* __restrict__ evTe,
    const int* __restrict__ evB, const int* __restrict__ meta,
    const int* __restrict__ hptr, float* __restrict__ S_ev)
{
  const int e = blockIdx.x % KSLOT, l = blockIdx.x / KSLOT;
  if(e >= meta[8]) return;
  const int tid = threadIdx.x;
  const int H = hptr[0];
  const int te = evTe[e], b = evB[e];
  int c = T_-1-te; if(c>H) c=H;
  const int cs = te>>5, ce = (te+c)>>5;
  const size_t sl = ((size_t)l*KSLOT + e)*D_ + tid*4;
  const float4 Rs = *(const float4*)(ckptS + sl);
  const float4 Re = *(const float4*)(ckptE + sl);
  const size_t ob = ((size_t)(l*B_+b)*NCC)*D_ + tid*4;
  const float4 Os = *(const float4*)(off + ob + (size_t)cs*D_);
  const float4 Oe = *(const float4*)(off + ob + (size_t)ce*D_);
  const float inv = 1.0f/(float)c;
  float4 fe;
  fe.x = ((Oe.x-Os.x) + (Re.x-Rs.x))*inv;
  fe.y = ((Oe.y-Os.y) + (Re.y-Rs.y))*inv;
  fe.z = ((Oe.z-Os.z) + (Re.z-Rs.z))*inv;
  fe.w = ((Oe.w-Os.w) + (Re.w-Rs.w))*inv;
  *(float4*)(ckptS + sl) = fe;
  float* sev = S_ev + l*D_ + tid*4;
  atomicAdd(sev+0, fe.x); atomicAdd(sev+1, fe.y);
  atomicAdd(sev+2, fe.z); atomicAdd(sev+3, fe.w);
}

// ---------------------------------------------------------------------------
// Kernel D: baseline EMA + excess sum over events (float4/thread)
// ---------------------------------------------------------------------------
__global__ __launch_bounds__(256) void kD(
    const float4* __restrict__ fe4, const int* __restrict__ meta,
    const float4* __restrict__ S_all4, const float4* __restrict__ S_ev4,
    const float4* __restrict__ baseline4, float4* __restrict__ out4,
    float* __restrict__ S_ex, int nonk)
{
  const int l = blockIdx.x / ES2, ech = blockIdx.x % ES2;
  const int tid = threadIdx.x;
  const int i4 = l*256 + tid;
  const float inv_nonk = 1.0f/(float)nonk;
  const float4 sa = S_all4[i4], se = S_ev4[i4], bl = baseline4[i4];
  float4 nb;
  nb.x = 0.99f*bl.x + 0.01f*((sa.x-se.x)*inv_nonk);
  nb.y = 0.99f*bl.y + 0.01f*((sa.y-se.y)*inv_nonk);
  nb.z = 0.99f*bl.z + 0.01f*((sa.z-se.z)*inv_nonk);
  nb.w = 0.99f*bl.w + 0.01f*((sa.w-se.w)*inv_nonk);
  if(ech == 0) out4[(L_*D_/4) + i4] = nb;
  const int nev = meta[8];
  const int chunk = (nev + ES2 - 1) / ES2;
  const int e0 = ech*chunk;
  int e1 = e0 + chunk; if(e1 > nev) e1 = nev;
  if(e1 <= e0) return;
  float4 acc = {0,0,0,0};
  #pragma unroll 4
  for(int e=e0;e<e1;++e){
    float4 fe = fe4[((size_t)l*KSLOT + e)*256 + tid];
    acc.x += fmaxf(fe.x - nb.x, 0.f);
    acc.y += fmaxf(fe.y - nb.y, 0.f);
    acc.z += fmaxf(fe.z - nb.z, 0.f);
    acc.w += fmaxf(fe.w - nb.w, 0.f);
  }
  float* sx = S_ex + l*D_ + tid*4;
  atomicAdd(sx+0, acc.x); atomicAdd(sx+1, acc.y);
  atomicAdd(sx+2, acc.z); atomicAdd(sx+3, acc.w);
}

// ---------------------------------------------------------------------------
// Kernel S2: age-weighted bank sums (float4/thread, grid L_*SCH2 = 256)
// ---------------------------------------------------------------------------
__global__ __launch_bounds__(256) void kS2(
    const float4* __restrict__ bank_ev4, const int* __restrict__ bank_step,
    const int* __restrict__ csptr, float* __restrict__ Sscore)
{
  const int l = blockIdx.x / SCH2, sch = blockIdx.x % SCH2;
  const int tid = threadIdx.x;
  const int scount = TTL_/SCH2;   // 32
  const int s0 = sch*scount;
  __shared__ float wl[scount];
  const int cs = csptr[0];
  if(tid < scount){
    int bs = bank_step[l*TTL_ + s0 + tid];
    float wgt = 0.f;
    if(bs >= 0){
      int a = cs - bs; if(a < 0) a = 0;
      wgt = exp2f(-(float)a * (1.0f/256.0f));
    }
    wl[tid] = wgt;
  }
  __syncthreads();
  float4 acc = {0,0,0,0};
  const float4* bp = bank_ev4 + ((size_t)l*TTL_ + s0)*256 + tid;
  #pragma unroll 8
  for(int j=0;j<scount;++j){
    float4 v = bp[(size_t)j*256];
    const float wv = wl[j];
    acc.x = fmaf(wv, v.x, acc.x); acc.y = fmaf(wv, v.y, acc.y);
    acc.z = fmaf(wv, v.z, acc.z); acc.w = fmaf(wv, v.w, acc.w);
  }
  float* sp2 = Sscore + l*D_ + tid*4;
  atomicAdd(sp2+0, acc.x); atomicAdd(sp2+1, acc.y);
  atomicAdd(sp2+2, acc.z); atomicAdd(sp2+3, acc.w);
}

// ---------------------------------------------------------------------------
// Kernel E: finalize evidence -> out[0] and score -> out[2]  (grid = L_)
// ---------------------------------------------------------------------------
__global__ __launch_bounds__(256) void kE(
    const float4* __restrict__ S_ex4, const float4* __restrict__ Sscore4,
    const int* __restrict__ bank_step, const int* __restrict__ csptr,
    float4* __restrict__ out4, float kf)
{
  const int l = blockIdx.x;
  const int tid = threadIdx.x;
  __shared__ float red[256];
  const int cs = csptr[0];
  float wacc = 0.f;
  for(int s=tid; s<TTL_; s+=256){
    int bs = bank_step[l*TTL_+s];
    if(bs >= 0){
      int a = cs - bs; if(a<0) a=0;
      wacc += exp2f(-(float)a * (1.0f/256.0f));
    }
  }
  red[tid] = wacc;
  __syncthreads();
  for(int st=128; st>0; st>>=1){ if(tid<st) red[tid] += red[tid+st]; __syncthreads(); }
  const float wsum = red[0];
  const int i4 = l*256 + tid;
  const float invk = 1.0f/kf;
  float4 ex = S_ex4[i4];
  float4 o0 = {ex.x*invk, ex.y*invk, ex.z*invk, ex.w*invk};
  out4[i4] = o0;
  float4 ss = Sscore4[i4];
  float4 o2 = {0,0,0,0};
  if(wsum > 0.f){
    const float wm = fmaxf(wsum, 1e-12f);
    o2.x = ss.x/wm; o2.y = ss.y/wm; o2.z = ss.z/wm; o2.w = ss.w/wm;
  }
  out4[2*(L_*D_/4) + i4] = o2;
}

// ---------------------------------------------------------------------------
extern "C" void kernel_launch(void* const* d_in, const int* in_sizes, int n_in,
                              void* d_out, int out_size, void* d_ws, size_t ws_size,
                              hipStream_t stream)
{
  const float* pressure  = (const float*)d_in[0];
  const float* states    = (const float*)d_in[1];
  const float* bank_ev   = (const float*)d_in[2];
  const float* baseline  = (const float*)d_in[3];
  const int*   bank_step = (const int*)d_in[4];
  const int*   csptr     = (const int*)d_in[5];
  const int*   hptr      = (const int*)d_in[6];
  float* out = (float*)d_out;

  const int total = B_*T_;
  const int k = (int)llround(0.05 * (double)total);   // 410

  // workspace layout (bytes)
  char* ws = (char*)d_ws;
  float* w        = (float*)(ws + 0);         // 8 KB
  int*   evT      = (int*)(ws + 8192);        // 8 KB
  int*   evE      = (int*)(ws + 16384);       // 8 KB
  int*   evTe     = (int*)(ws + 24576);       // 2 KB
  int*   evB      = (int*)(ws + 26624);       // 2 KB
  int*   meta     = (int*)(ws + 28672);       // 64 B
  float* S_all    = (float*)(ws + 32768);     // 32 KB
  float* S_ev     = (float*)(ws + 65536);     // 32 KB
  float* S_ex     = (float*)(ws + 98304);     // 32 KB
  float* Sscore   = (float*)(ws + 131072);    // 32 KB
  float* chunkSum = (float*)(ws + 163840);            // 8 MB
  float* offBuf   = (float*)(ws + 163840 + 8388608);  // 8 MB
  float* ckptS    = (float*)(ws + 163840 + 16777216); // 16 MB
  float* ckptE    = (float*)(ws + 163840 + 33554432); // 16 MB

  const size_t need = 163840 + 8388608ull*2 + 16777216ull*2;
  if(ws_size < need) return;

  kA<<<1, 1024, 0, stream>>>(pressure, hptr, k, evT, evE, evTe, evB, meta, w,
                             (float4*)S_all);
  kB<<<L_*B_*NCC, 256, 0, stream>>>(states, w, evT, evE, meta,
                                    S_all, chunkSum, ckptS, ckptE);
  kP<<<L_*B_*4, 64, 0, stream>>>((const float4*)chunkSum, (float4*)offBuf);
  kF<<<L_*KSLOT, 256, 0, stream>>>(ckptE, ckptS, offBuf, evTe, evB, meta,
                                   hptr, S_ev);
  kD<<<L_*ES2, 256, 0, stream>>>((const float4*)ckptS, meta, (const float4*)S_all,
                                 (const float4*)S_ev, (const float4*)baseline,
                                 (float4*)out, S_ex, total - k);
  kS2<<<L_*SCH2, 256, 0, stream>>>((const float4*)bank_ev, bank_step, csptr, Sscore);
  kE<<<L_, 256, 0, stream>>>((const float4*)S_ex, (const float4*)Sscore,
                             bank_step, csptr, (float4*)out, (float)k);
}

// Round 7
// 306.922 us; speedup vs baseline: 1.1144x; 1.1144x over previous
//
#include <hip/hip_runtime.h>
#include <cmath>
#include <climits>

// Fixed problem shape (from setup_inputs)
#define L_    8
#define B_    4
#define T_    2048
#define D_    1024
#define TTL_  1024
#define KSLOT 512          // flat event slot capacity (k=410)
#define TOTSEG 832         // segment slot pool (max 2k+B = 824)
#define GROUP 4            // segments per kB1 block
#define NG    (TOTSEG/GROUP)  // 208
#define ES2   32           // event-split for excess kernel
#define SCH2  32           // s-split for score kernel
#define TIEMAX 256

__device__ __forceinline__ int waveRed(int v){
  for(int o=32;o>0;o>>=1) v += __shfl_xor(v,o,64);
  return v;
}

// ---------------------------------------------------------------------------
// Kernel A: zero accumulators; top-k (2-bit radix, exact jax tie-break);
// per-batch event lists; mark-merge ranking -> segment slot pool
// (segLo/segHi/segB), emit maps (emitS/emitE), evInv; weight w[s].
// One block, 1024 threads.
// ---------------------------------------------------------------------------
__global__ __launch_bounds__(1024) void kA(
    const float* __restrict__ pressure, const int* __restrict__ hptr,
    int k, int* __restrict__ meta, float* __restrict__ w,
    float* __restrict__ evInv, int* __restrict__ segLo, int* __restrict__ segHi,
    int* __restrict__ segB, int* __restrict__ emitS, int* __restrict__ emitE,
    float4* __restrict__ zeroRegion /* S_all..Sscore, 32768 floats */)
{
  {
    float4 z = {0,0,0,0};
    #pragma unroll
    for(int j=0;j<8;++j) zeroRegion[threadIdx.x + j*1024] = z;
  }

  __shared__ unsigned ku[B_*T_];
  __shared__ short ef[B_*T_];
  __shared__ int csum[1024];
  __shared__ int cnt4[4][4];
  __shared__ int scnt;
  __shared__ int s_n[B_];
  __shared__ int s_off[B_];
  __shared__ int segBase_sh[B_];
  __shared__ int tieIdx[TIEMAX];
  __shared__ int tieCnt;
  __shared__ short evTeSh[B_*KSLOT];
  __shared__ short evEnSh[B_*KSLOT];
  __shared__ short markVal[TOTSEG];
  const int tid = threadIdx.x;
  const int total = B_*T_;
  const int H = hptr[0];

  for(int i=tid;i<total;i+=1024){
    union{float f;unsigned u;} v; v.f = pressure[i];
    unsigned u = v.u;
    ku[i] = (u & 0x80000000u) ? ~u : (u | 0x80000000u);  // monotonic key
  }
  if(tid < B_) s_n[tid] = 0;
  if(tid == 0) tieCnt = 0;
  if(tid < 8) ((int*)cnt4)[tid] = 0;
  __syncthreads();

  // 2-bit radix k-th-largest: 16 iterations, 1 barrier each.
  unsigned p = 0;
  for(int it=0; it<16; ++it){
    const int bit = 30 - 2*it;
    int* A = cnt4[it&3];
    const unsigned q1 = p | (1u<<bit);
    const unsigned q2 = p | (2u<<bit);
    const unsigned q3 = p | (3u<<bit);
    int c1=0,c2=0,c3=0;
    for(int i=tid;i<total;i+=1024){
      unsigned x = ku[i];
      c1 += (x>=q1); c2 += (x>=q2); c3 += (x>=q3);
    }
    c1=waveRed(c1); c2=waveRed(c2); c3=waveRed(c3);
    if((tid&63)==0){ atomicAdd(&A[1],c1); atomicAdd(&A[2],c2); atomicAdd(&A[3],c3); }
    if(tid<4) cnt4[(it+2)&3][tid] = 0;
    __syncthreads();
    const int n1=A[1], n2=A[2], n3=A[3];
    if(n3>=k) p=q3; else if(n2>=k) p=q2; else if(n1>=k) p=q1;
  }
  __syncthreads();
  if(tid==0) scnt=0;
  __syncthreads();
  {
    int c=0;
    for(int i=tid;i<total;i+=1024) c += (ku[i] > p) ? 1 : 0;
    c = waveRed(c);
    if((tid&63)==0) atomicAdd(&scnt, c);
  }
  for(int i=tid;i<total;i+=1024){
    if(ku[i]==p){ int pos=atomicAdd(&tieCnt,1); if(pos<TIEMAX) tieIdx[pos]=i; }
  }
  __syncthreads();
  const int needed = k - scnt;

  for(int j=0;j<8;++j){
    int i = tid*8+j;
    ef[i] = (ku[i] > p) ? (short)1 : (short)0;
  }
  __syncthreads();

  if(tieCnt <= TIEMAX){
    if(tid==0){
      int cnt = tieCnt;
      for(int sel=0; sel<needed; ++sel){
        int best=INT_MAX, bi=-1;
        for(int q=0;q<cnt;++q){ int vv=tieIdx[q]; if(vv>=0 && vv<best){best=vv;bi=q;} }
        if(bi>=0){ tieIdx[bi]=-1; ef[best]=1; }
      }
    }
  } else {
    for(int j=0;j<8;++j){
      int i = tid*8+j;
      if(ku[i]==p){
        int r=0;
        for(int q=0;q<i;++q) r += (ku[q]==p) ? 1 : 0;
        if(r < needed) ef[i]=1;
      }
    }
  }
  __syncthreads();

  {
    int local=0;
    for(int j=0;j<8;++j) local += ef[tid*8+j];
    csum[tid]=local;
  }
  __syncthreads();

  // per-batch sorted event lists in shared (skip c==0, i.e. te==T-1)
  for(int j=0;j<8;++j){
    int i = tid*8+j;
    if(ef[i]){
      int b = i / T_, t = i % T_;
      int c = T_-1-t; if(c>H) c=H;
      if(c > 0){
        int m = 0;
        int ch = i>>3;
        for(int q=(b*T_)>>3; q<ch; ++q) m += csum[q];
        for(int q=ch<<3; q<i; ++q) m += ef[q];
        evTeSh[b*KSLOT + m] = (short)t;
        evEnSh[b*KSLOT + m] = (short)(t + c);
        atomicAdd(&s_n[b], 1);
      }
    }
  }
  __syncthreads();
  if(tid==0){
    int off=0, sb=0;
    for(int b=0;b<B_;++b){
      meta[b]=s_n[b]; meta[4+b]=off; s_off[b]=off; off += s_n[b];
      meta[9+b]=sb; segBase_sh[b]=sb;
      int ns = 2*s_n[b]+1; meta[13+b]=ns; sb += ns;
    }
    meta[8] = off;  // total listed events
  }
  // init emit maps
  for(int s=tid; s<TOTSEG; s+=1024){ emitS[s] = -1; emitE[s] = -1; }
  __syncthreads();

  // mark-merge ranking per event (ends-before-starts on value ties)
  for(int idx=tid; idx<B_*KSLOT; idx+=1024){
    const int b = idx >> 9, j = idx & (KSLOT-1);
    const int n = s_n[b];
    if(j >= n) continue;
    const int te = evTeSh[b*KSLOT+j];
    const int en = evEnSh[b*KSLOT+j];
    int cle=0, clt=0, ceq=0, cst=0;
    for(int i=0;i<n;++i){
      int ei = evEnSh[b*KSLOT+i];
      cle += (ei <= te);
      clt += (ei < en);
      ceq += (ei == en && i < j);
      cst += ((int)evTeSh[b*KSLOT+i] < en);
    }
    const int rs = j + cle;             // rank of start mark
    const int re = clt + ceq + cst;     // rank of end mark
    const int gb = segBase_sh[b];
    markVal[gb + rs] = (short)te;
    markVal[gb + re] = (short)en;
    const int e = s_off[b] + j;
    emitS[gb + rs] = e;
    emitE[gb + re] = e;
    evInv[e] = 1.0f/(float)(en - te);
  }
  __syncthreads();

  // derive per-slot row ranges
  for(int s=tid; s<TOTSEG; s+=1024){
    int b=-1, i=0;
    for(int q=0;q<B_;++q){
      int sb = segBase_sh[q], ns = 2*s_n[q]+1;
      if(s >= sb && s < sb+ns){ b=q; i=s-sb; }
    }
    int lo, hi, bb;
    if(b < 0){ lo=1; hi=0; bb=0; }          // inactive slot: empty
    else{
      const int m = 2*s_n[b];
      hi = (i < m) ? (int)markVal[s] : (T_-1);
      lo = (i == 0) ? 0 : ((int)markVal[s-1] + 1);
      bb = b;
    }
    segLo[s]=lo; segHi[s]=hi; segB[s]=bb;
  }

  // w[s] = sum_{t'=max(0,s-H)}^{s-1} 1/min(H, T-1-t')
  for(int s=tid;s<T_;s+=1024){
    float acc = 0.f;
    int lo = s - H; if(lo < 0) lo = 0;
    for(int t2=lo; t2<s; ++t2){
      int c2 = T_-1-t2; if(c2 > H) c2 = H;
      acc += 1.0f / (float)c2;
    }
    w[s] = acc;
  }
}

// ---------------------------------------------------------------------------
// Kernel B1: pure streaming. One block per 4 segments; per segment: sum of
// squares (R, -> segSum row) and w-weighted sum (A, -> S_all atomics).
// NO shared memory, NO barriers, NO data-dependent branches in the body.
// Grid L_*NG = 1664 blocks x 256 threads (float4/thread = full row).
// ---------------------------------------------------------------------------
__global__ __launch_bounds__(256) void kB1(
    const float* __restrict__ states, const float* __restrict__ w,
    const int* __restrict__ segLo, const int* __restrict__ segHi,
    const int* __restrict__ segB,
    float* __restrict__ S_all, float4* __restrict__ segSum4)
{
  const int l  = blockIdx.x / NG;
  const int g0 = (blockIdx.x % NG)*GROUP;
  const int tid = threadIdx.x;
  float4 A = {0,0,0,0};
  for(int g=0; g<GROUP; ++g){
    const int slot = g0 + g;
    const int b  = segB[slot];
    const int lo = segLo[slot];
    const int hi = segHi[slot];
    const float4* sp = (const float4*)(states + ((size_t)(l*B_+b)*T_)*D_) + tid;
    float4 R = {0,0,0,0};
    int t = lo;
    if(t <= hi){
      float4 x = sp[(size_t)t*256];
      while(t < hi){
        float4 xn = sp[(size_t)(t+1)*256];
        const float wv = w[t];
        float sx=x.x*x.x, sy=x.y*x.y, sz=x.z*x.z, sw=x.w*x.w;
        R.x+=sx; R.y+=sy; R.z+=sz; R.w+=sw;
        A.x=fmaf(wv,sx,A.x); A.y=fmaf(wv,sy,A.y);
        A.z=fmaf(wv,sz,A.z); A.w=fmaf(wv,sw,A.w);
        x = xn; ++t;
      }
      const float wv = w[hi];
      float sx=x.x*x.x, sy=x.y*x.y, sz=x.z*x.z, sw=x.w*x.w;
      R.x+=sx; R.y+=sy; R.z+=sz; R.w+=sw;
      A.x=fmaf(wv,sx,A.x); A.y=fmaf(wv,sy,A.y);
      A.z=fmaf(wv,sz,A.z); A.w=fmaf(wv,sw,A.w);
    }
    segSum4[((size_t)l*TOTSEG + slot)*256 + tid] = R;
  }
  float* sa = S_all + l*D_ + tid*4;
  atomicAdd(sa+0, A.x); atomicAdd(sa+1, A.y);
  atomicAdd(sa+2, A.z); atomicAdd(sa+3, A.w);
}

// ---------------------------------------------------------------------------
// Kernel PF: per (l,b), serial scan over segment sums = prefix P at every
// mark; at start-marks stash P row into feBuf; at end-marks
// fe = (P_end - P_start)*inv -> feBuf (in place), S_ev in registers.
// Grid L_*B_ = 32 blocks x 256 threads.
// ---------------------------------------------------------------------------
__global__ __launch_bounds__(256) void kPF(
    const float4* __restrict__ segSum4, const int* __restrict__ meta,
    const int* __restrict__ emitS, const int* __restrict__ emitE,
    const float* __restrict__ evInv, float4* __restrict__ feBuf4,
    float* __restrict__ S_ev)
{
  const int b = blockIdx.x % B_, l = blockIdx.x / B_;
  const int tid = threadIdx.x;
  const int sbase = meta[9+b];
  const int nseg  = meta[13+b];
  float4 acc = {0,0,0,0}, E = {0,0,0,0};
  for(int i=0;i<nseg;++i){
    const int slot = sbase + i;
    float4 v = segSum4[((size_t)l*TOTSEG + slot)*256 + tid];
    acc.x+=v.x; acc.y+=v.y; acc.z+=v.z; acc.w+=v.w;
    const int es = emitS[slot];
    if(es >= 0) feBuf4[((size_t)l*KSLOT + es)*256 + tid] = acc;
    const int ee = emitE[slot];
    if(ee >= 0){
      float4 st = feBuf4[((size_t)l*KSLOT + ee)*256 + tid];
      const float inv = evInv[ee];
      float4 fe = {(acc.x-st.x)*inv, (acc.y-st.y)*inv,
                   (acc.z-st.z)*inv, (acc.w-st.w)*inv};
      feBuf4[((size_t)l*KSLOT + ee)*256 + tid] = fe;
      E.x+=fe.x; E.y+=fe.y; E.z+=fe.z; E.w+=fe.w;
    }
  }
  float* se = S_ev + l*D_ + tid*4;
  atomicAdd(se+0, E.x); atomicAdd(se+1, E.y);
  atomicAdd(se+2, E.z); atomicAdd(se+3, E.w);
}

// ---------------------------------------------------------------------------
// Kernel DS2 (fused): blocks [0,256): baseline EMA + excess sum over events;
// blocks [256,512): age-weighted bank sums.
// ---------------------------------------------------------------------------
__global__ __launch_bounds__(256) void kDS2(
    const float4* __restrict__ feBuf4, const int* __restrict__ meta,
    const float4* __restrict__ S_all4, const float4* __restrict__ S_ev4,
    const float4* __restrict__ baseline4,
    const float4* __restrict__ bank_ev4, const int* __restrict__ bank_step,
    const int* __restrict__ csptr,
    float4* __restrict__ out4, float* __restrict__ S_ex,
    float* __restrict__ Sscore, int nonk)
{
  const int tid = threadIdx.x;
  if(blockIdx.x < L_*ES2){
    const int l = blockIdx.x / ES2, ech = blockIdx.x % ES2;
    const int i4 = l*256 + tid;
    const float inv_nonk = 1.0f/(float)nonk;
    const float4 sa = S_all4[i4], se = S_ev4[i4], bl = baseline4[i4];
    float4 nb;
    nb.x = 0.99f*bl.x + 0.01f*((sa.x-se.x)*inv_nonk);
    nb.y = 0.99f*bl.y + 0.01f*((sa.y-se.y)*inv_nonk);
    nb.z = 0.99f*bl.z + 0.01f*((sa.z-se.z)*inv_nonk);
    nb.w = 0.99f*bl.w + 0.01f*((sa.w-se.w)*inv_nonk);
    if(ech == 0) out4[(L_*D_/4) + i4] = nb;
    const int nev = meta[8];
    const int chunk = (nev + ES2 - 1) / ES2;
    const int e0 = ech*chunk;
    int e1 = e0 + chunk; if(e1 > nev) e1 = nev;
    if(e1 <= e0) return;
    float4 acc = {0,0,0,0};
    #pragma unroll 4
    for(int e=e0;e<e1;++e){
      float4 fe = feBuf4[((size_t)l*KSLOT + e)*256 + tid];
      acc.x += fmaxf(fe.x - nb.x, 0.f);
      acc.y += fmaxf(fe.y - nb.y, 0.f);
      acc.z += fmaxf(fe.z - nb.z, 0.f);
      acc.w += fmaxf(fe.w - nb.w, 0.f);
    }
    float* sx = S_ex + l*D_ + tid*4;
    atomicAdd(sx+0, acc.x); atomicAdd(sx+1, acc.y);
    atomicAdd(sx+2, acc.z); atomicAdd(sx+3, acc.w);
  } else {
    const int bx = blockIdx.x - L_*ES2;
    const int l = bx / SCH2, sch = bx % SCH2;
    const int scount = TTL_/SCH2;   // 32
    const int s0 = sch*scount;
    __shared__ float wl[TTL_/SCH2];
    const int cs = csptr[0];
    if(tid < scount){
      int bs = bank_step[l*TTL_ + s0 + tid];
      float wgt = 0.f;
      if(bs >= 0){
        int a = cs - bs; if(a < 0) a = 0;
        wgt = exp2f(-(float)a * (1.0f/256.0f));
      }
      wl[tid] = wgt;
    }
    __syncthreads();
    float4 acc = {0,0,0,0};
    const float4* bp = bank_ev4 + ((size_t)l*TTL_ + s0)*256 + tid;
    #pragma unroll 8
    for(int j=0;j<scount;++j){
      float4 v = bp[(size_t)j*256];
      const float wv = wl[j];
      acc.x = fmaf(wv, v.x, acc.x); acc.y = fmaf(wv, v.y, acc.y);
      acc.z = fmaf(wv, v.z, acc.z); acc.w = fmaf(wv, v.w, acc.w);
    }
    float* sp2 = Sscore + l*D_ + tid*4;
    atomicAdd(sp2+0, acc.x); atomicAdd(sp2+1, acc.y);
    atomicAdd(sp2+2, acc.z); atomicAdd(sp2+3, acc.w);
  }
}

// ---------------------------------------------------------------------------
// Kernel E: finalize evidence -> out[0] and score -> out[2]  (grid = L_)
// ---------------------------------------------------------------------------
__global__ __launch_bounds__(256) void kE(
    const float4* __restrict__ S_ex4, const float4* __restrict__ Sscore4,
    const int* __restrict__ bank_step, const int* __restrict__ csptr,
    float4* __restrict__ out4, float kf)
{
  const int l = blockIdx.x;
  const int tid = threadIdx.x;
  __shared__ float red[256];
  const int cs = csptr[0];
  float wacc = 0.f;
  for(int s=tid; s<TTL_; s+=256){
    int bs = bank_step[l*TTL_+s];
    if(bs >= 0){
      int a = cs - bs; if(a<0) a=0;
      wacc += exp2f(-(float)a * (1.0f/256.0f));
    }
  }
  red[tid] = wacc;
  __syncthreads();
  for(int st=128; st>0; st>>=1){ if(tid<st) red[tid] += red[tid+st]; __syncthreads(); }
  const float wsum = red[0];
  const int i4 = l*256 + tid;
  const float invk = 1.0f/kf;
  float4 ex = S_ex4[i4];
  float4 o0 = {ex.x*invk, ex.y*invk, ex.z*invk, ex.w*invk};
  out4[i4] = o0;
  float4 ss = Sscore4[i4];
  float4 o2 = {0,0,0,0};
  if(wsum > 0.f){
    const float wm = fmaxf(wsum, 1e-12f);
    o2.x = ss.x/wm; o2.y = ss.y/wm; o2.z = ss.z/wm; o2.w = ss.w/wm;
  }
  out4[2*(L_*D_/4) + i4] = o2;
}

// ---------------------------------------------------------------------------
extern "C" void kernel_launch(void* const* d_in, const int* in_sizes, int n_in,
                              void* d_out, int out_size, void* d_ws, size_t ws_size,
                              hipStream_t stream)
{
  const float* pressure  = (const float*)d_in[0];
  const float* states    = (const float*)d_in[1];
  const float* bank_ev   = (const float*)d_in[2];
  const float* baseline  = (const float*)d_in[3];
  const int*   bank_step = (const int*)d_in[4];
  const int*   csptr     = (const int*)d_in[5];
  const int*   hptr      = (const int*)d_in[6];
  float* out = (float*)d_out;

  const int total = B_*T_;
  const int k = (int)llround(0.05 * (double)total);   // 410

  // workspace layout (bytes)
  char* ws = (char*)d_ws;
  float* w      = (float*)(ws + 0);         // 8 KB
  int*   meta   = (int*)(ws + 8192);        // 128 B
  float* evInv  = (float*)(ws + 12288);     // 2 KB
  int*   segLo  = (int*)(ws + 16384);       // 4 KB
  int*   segHi  = (int*)(ws + 20480);       // 4 KB
  int*   segB   = (int*)(ws + 24576);       // 4 KB
  int*   emitS  = (int*)(ws + 28672);       // 4 KB
  int*   emitE  = (int*)(ws + 32768);       // 4 KB
  float* S_all  = (float*)(ws + 40960);     // 32 KB
  float* S_ev   = (float*)(ws + 73728);     // 32 KB
  float* S_ex   = (float*)(ws + 106496);    // 32 KB
  float* Sscore = (float*)(ws + 139264);    // 32 KB
  float* segSum = (float*)(ws + 172032);                 // 8*832*4KB = 27.26 MB
  float* feBuf  = (float*)(ws + 172032 + 27262976);      // 8*512*4KB = 16.78 MB

  const size_t need = 172032ull + 27262976ull + 16777216ull;  // 44.2 MB
  if(ws_size < need) return;

  kA<<<1, 1024, 0, stream>>>(pressure, hptr, k, meta, w, evInv,
                             segLo, segHi, segB, emitS, emitE, (float4*)S_all);
  kB1<<<L_*NG, 256, 0, stream>>>(states, w, segLo, segHi, segB,
                                 S_all, (float4*)segSum);
  kPF<<<L_*B_, 256, 0, stream>>>((const float4*)segSum, meta, emitS, emitE,
                                 evInv, (float4*)feBuf, S_ev);
  kDS2<<<L_*ES2 + L_*SCH2, 256, 0, stream>>>((const float4*)feBuf, meta,
                                 (const float4*)S_all, (const float4*)S_ev,
                                 (const float4*)baseline, (const float4*)bank_ev,
                                 bank_step, csptr, (float4*)out, S_ex, Sscore,
                                 total - k);
  kE<<<L_, 256, 0, stream>>>((const float4*)S_ex, (const float4*)Sscore,
                             bank_step, csptr, (float4*)out, (float)k);
}

// Round 8
// 237.956 us; speedup vs baseline: 1.4374x; 1.2898x over previous
//
#include <hip/hip_runtime.h>
#include <cmath>
#include <climits>

// Fixed problem shape
#define L_    8
#define B_    4
#define T_    2048
#define D_    1024
#define TTL_  1024
#define KSLOT 512
#define EVCAP 512
#define TCQ   16           // rows per chunk
#define NCQ   (T_/TCQ)     // 128 chunks per (l,b)
#define EGRP  64           // event groups per l (kFE)
#define EPG   8            // events per group
#define TIEMAX 256
#define MAXMB 1024         // mark slots per batch

__device__ __forceinline__ int waveRed(int v){
  for(int o=32;o>0;o>>=1) v += __shfl_xor(v,o,64);
  return v;
}

// ---------------------------------------------------------------------------
// Kernel A: top-k (2-bit radix, exact jax tie-break); per-batch event lists;
// batch-sorted merged mark list (row-sorted starts+ends) + per-(b,chunk)
// descriptors; flat event metadata; weight w[s]. One block, 1024 threads.
// ---------------------------------------------------------------------------
__global__ __launch_bounds__(1024) void kA(
    const float* __restrict__ pressure, const int* __restrict__ hptr, int k,
    int* __restrict__ meta, float* __restrict__ w,
    int* __restrict__ evB, int* __restrict__ evCS, int* __restrict__ evCE,
    float* __restrict__ evInv,
    unsigned short* __restrict__ markRowG, unsigned short* __restrict__ markValG,
    int* __restrict__ mkStart, int* __restrict__ mkCnt)
{
  __shared__ unsigned ku[B_*T_];
  __shared__ short ef[B_*T_];
  __shared__ int csum[1024];
  __shared__ int cnt4[4][4];
  __shared__ int scnt;
  __shared__ int s_n[B_], s_off[B_];
  __shared__ int tieIdx[TIEMAX];
  __shared__ int tieCnt;
  __shared__ short evTeSh[B_*KSLOT];
  __shared__ short evEnSh[B_*KSLOT];
  __shared__ unsigned short mrowS[B_*MAXMB];
  const int tid = threadIdx.x;
  const int total = B_*T_;
  const int H = hptr[0];

  for(int i=tid;i<total;i+=1024){
    union{float f;unsigned u;} v; v.f = pressure[i];
    unsigned u = v.u;
    ku[i] = (u & 0x80000000u) ? ~u : (u | 0x80000000u);
  }
  if(tid < B_) s_n[tid] = 0;
  if(tid == 0) tieCnt = 0;
  if(tid < 8) ((int*)cnt4)[tid] = 0;
  __syncthreads();

  // 2-bit radix k-th-largest
  unsigned p = 0;
  for(int it=0; it<16; ++it){
    const int bit = 30 - 2*it;
    int* A = cnt4[it&3];
    const unsigned q1 = p | (1u<<bit);
    const unsigned q2 = p | (2u<<bit);
    const unsigned q3 = p | (3u<<bit);
    int c1=0,c2=0,c3=0;
    for(int i=tid;i<total;i+=1024){
      unsigned x = ku[i];
      c1 += (x>=q1); c2 += (x>=q2); c3 += (x>=q3);
    }
    c1=waveRed(c1); c2=waveRed(c2); c3=waveRed(c3);
    if((tid&63)==0){ atomicAdd(&A[1],c1); atomicAdd(&A[2],c2); atomicAdd(&A[3],c3); }
    if(tid<4) cnt4[(it+2)&3][tid] = 0;
    __syncthreads();
    const int n1=A[1], n2=A[2], n3=A[3];
    if(n3>=k) p=q3; else if(n2>=k) p=q2; else if(n1>=k) p=q1;
  }
  __syncthreads();
  if(tid==0) scnt=0;
  __syncthreads();
  {
    int c=0;
    for(int i=tid;i<total;i+=1024) c += (ku[i] > p) ? 1 : 0;
    c = waveRed(c);
    if((tid&63)==0) atomicAdd(&scnt, c);
  }
  for(int i=tid;i<total;i+=1024){
    if(ku[i]==p){ int pos=atomicAdd(&tieCnt,1); if(pos<TIEMAX) tieIdx[pos]=i; }
  }
  __syncthreads();
  const int needed = k - scnt;

  for(int j=0;j<8;++j){
    int i = tid*8+j;
    ef[i] = (ku[i] > p) ? (short)1 : (short)0;
  }
  __syncthreads();

  if(tieCnt <= TIEMAX){
    if(tid==0){
      int cnt = tieCnt;
      for(int sel=0; sel<needed; ++sel){
        int best=INT_MAX, bi=-1;
        for(int q=0;q<cnt;++q){ int vv=tieIdx[q]; if(vv>=0 && vv<best){best=vv;bi=q;} }
        if(bi>=0){ tieIdx[bi]=-1; ef[best]=1; }
      }
    }
  } else {
    for(int j=0;j<8;++j){
      int i = tid*8+j;
      if(ku[i]==p){
        int r=0;
        for(int q=0;q<i;++q) r += (ku[q]==p) ? 1 : 0;
        if(r < needed) ef[i]=1;
      }
    }
  }
  __syncthreads();

  {
    int local=0;
    for(int j=0;j<8;++j) local += ef[tid*8+j];
    csum[tid]=local;
  }
  __syncthreads();

  // per-batch sorted event lists (skip c==0, i.e. te==T-1)
  for(int j=0;j<8;++j){
    int i = tid*8+j;
    if(ef[i]){
      int b = i / T_, t = i % T_;
      int c = T_-1-t; if(c>H) c=H;
      if(c > 0){
        int m = 0;
        int ch = i>>3;
        for(int q=(b*T_)>>3; q<ch; ++q) m += csum[q];
        for(int q=ch<<3; q<i; ++q) m += ef[q];
        evTeSh[b*KSLOT + m] = (short)t;
        evEnSh[b*KSLOT + m] = (short)(t + c);
        atomicAdd(&s_n[b], 1);
      }
    }
  }
  __syncthreads();
  if(tid==0){
    int off=0;
    for(int b=0;b<B_;++b){ meta[b]=s_n[b]; meta[4+b]=off; s_off[b]=off; off += s_n[b]; }
    meta[8] = off;  // nev
  }
  __syncthreads();

  // merged mark ranking (sorted by row; tie-break by mark index) + flat event meta
  for(int idx=tid; idx<B_*MAXMB; idx+=1024){
    const int b = idx>>10, m = idx & (MAXMB-1);
    const int n = s_n[b];
    if(m >= 2*n) continue;
    const int bK = b*KSLOT;
    const int r = (m<n) ? (int)evTeSh[bK+m] : (int)evEnSh[bK+m-n];
    int rank = 0;
    for(int i=0;i<2*n;++i){
      int ri = (i<n) ? (int)evTeSh[bK+i] : (int)evEnSh[bK+i-n];
      rank += (ri < r) || (ri == r && i < m);
    }
    const int e = s_off[b] + ((m<n) ? m : m-n);
    mrowS[b*MAXMB+rank]   = (unsigned short)r;
    markRowG[b*MAXMB+rank]= (unsigned short)r;
    markValG[b*MAXMB+rank]= (unsigned short)(e | ((m<n) ? 0 : 0x8000));
    if(m<n){
      const int en = (int)evEnSh[bK+m];
      evB[e]=b; evCS[e]=r>>4; evCE[e]=en>>4;
      evInv[e] = 1.0f/(float)(en - r);
    }
  }
  __syncthreads();

  // per-(b,chunk) mark descriptors
  for(int idx=tid; idx<B_*NCQ; idx+=1024){
    const int b = idx/NCQ, ch = idx%NCQ;
    const int n2 = 2*s_n[b];
    const int lo = ch*TCQ, hi = lo+TCQ;
    int a=0,c=0;
    for(int i=0;i<n2;++i){
      int r = (int)mrowS[b*MAXMB+i];
      a += (r < lo); c += (r < hi);
    }
    mkStart[idx] = a; mkCnt[idx] = c - a;
  }

  // w[s] = sum_{t'=max(0,s-H)}^{s-1} 1/min(H, T-1-t')
  for(int s=tid;s<T_;s+=1024){
    float acc = 0.f;
    int lo = s - H; if(lo < 0) lo = 0;
    for(int t2=lo; t2<s; ++t2){
      int c2 = T_-1-t2; if(c2 > H) c2 = H;
      acc += 1.0f / (float)c2;
    }
    w[s] = acc;
  }
}

// ---------------------------------------------------------------------------
// Kernel SQ: THE streaming pass. One block per (l,b,16-row chunk).
// All 16 row loads issued as one unconditional unrolled register batch,
// then pure-register prefix/weighted compute; marks emit register R rows.
// Writes: chunkCS row, wA row, feS/feE mark rows. NO atomics, NO barriers.
// ---------------------------------------------------------------------------
__global__ __launch_bounds__(256) void kSQ(
    const float* __restrict__ states, const float* __restrict__ w,
    const int* __restrict__ mkStart, const int* __restrict__ mkCnt,
    const unsigned short* __restrict__ markRowG,
    const unsigned short* __restrict__ markValG,
    float4* __restrict__ chunkCS, float4* __restrict__ wA,
    float4* __restrict__ feS, float4* __restrict__ feE)
{
  int bx = blockIdx.x;
  const int ch = bx % NCQ; bx /= NCQ;
  const int b = bx % B_; const int l = bx / B_;
  const int tid = threadIdx.x;
  const int t0 = ch*TCQ;
  const float4* sp = (const float4*)states + ((size_t)(l*B_+b)*T_)*256 + tid;

  float4 v[16];
  #pragma unroll
  for(int j=0;j<16;++j) v[j] = sp[(size_t)(t0+j)*256];
  float wv[16];
  #pragma unroll
  for(int j=0;j<16;++j) wv[j] = w[t0+j];

  int mi   = mkStart[b*NCQ+ch];
  int mrem = mkCnt[b*NCQ+ch];
  const unsigned short* mr = markRowG + b*MAXMB;
  const unsigned short* mv = markValG + b*MAXMB;
  int nextRow = (mrem>0) ? (int)mr[mi] : INT_MAX;

  float4 R={0,0,0,0}, A={0,0,0,0};
  #pragma unroll
  for(int j=0;j<16;++j){
    float4 x = v[j];
    float sx=x.x*x.x, sy=x.y*x.y, sz=x.z*x.z, sw=x.w*x.w;
    R.x+=sx; R.y+=sy; R.z+=sz; R.w+=sw;
    const float wj = wv[j];
    A.x=fmaf(wj,sx,A.x); A.y=fmaf(wj,sy,A.y);
    A.z=fmaf(wj,sz,A.z); A.w=fmaf(wj,sw,A.w);
    while(nextRow == t0+j){
      const int me = (int)mv[mi];
      float4* dst = (me & 0x8000) ? feE : feS;
      dst[((size_t)l*EVCAP + (me & 0x7fff))*256 + tid] = R;
      ++mi; --mrem;
      nextRow = (mrem>0) ? (int)mr[mi] : INT_MAX;
    }
  }
  const size_t ci = ((size_t)(l*B_+b)*NCQ + ch)*256 + tid;
  chunkCS[ci] = R;
  wA[ci] = A;
}

// ---------------------------------------------------------------------------
// Kernel Scan: per (l,b,d-quarter): in-place exclusive scan of chunkCS over
// 128 chunks (-> chunkOff) + reduction of wA -> S_allB row. Batch-8 loads.
// ---------------------------------------------------------------------------
__global__ __launch_bounds__(256) void kScan(
    float* __restrict__ chunkCS, const float* __restrict__ wA,
    float* __restrict__ S_allB)
{
  const int q = blockIdx.x & 3; const int lb = blockIdx.x >> 2;
  const int d = q*256 + threadIdx.x;
  const size_t base = (size_t)lb*NCQ*D_ + d;
  float acc = 0.f, aw = 0.f;
  for(int c0=0;c0<NCQ;c0+=8){
    float vv[8], wv[8];
    #pragma unroll
    for(int j=0;j<8;++j){
      vv[j] = chunkCS[base + (size_t)(c0+j)*D_];
      wv[j] = wA[base + (size_t)(c0+j)*D_];
    }
    #pragma unroll
    for(int j=0;j<8;++j){
      chunkCS[base + (size_t)(c0+j)*D_] = acc;
      acc += vv[j]; aw += wv[j];
    }
  }
  S_allB[(size_t)lb*D_ + d] = aw;
}

// ---------------------------------------------------------------------------
// Kernel FE: per (l, group of 8 events): fe = ((Oe+Re)-(Os+Rs))*inv -> feE;
// per-group S_ev partial row (no atomics).
// ---------------------------------------------------------------------------
__global__ __launch_bounds__(256) void kFE(
    const float4* __restrict__ feS, float4* __restrict__ feE,
    const float4* __restrict__ chunkOff,
    const int* __restrict__ evB, const int* __restrict__ evCS,
    const int* __restrict__ evCE, const float* __restrict__ evInv,
    const int* __restrict__ meta, float4* __restrict__ S_evP)
{
  const int g = blockIdx.x & (EGRP-1); const int l = blockIdx.x / EGRP;
  const int tid = threadIdx.x;
  const int nev = meta[8];
  float4 E = {0,0,0,0};
  for(int j=0;j<EPG;++j){
    const int e = g*EPG + j;
    if(e >= nev) break;
    const int b = evB[e];
    const size_t ob = ((size_t)(l*B_+b)*NCQ)*256 + tid;
    float4 Os = chunkOff[ob + (size_t)evCS[e]*256];
    float4 Oe = chunkOff[ob + (size_t)evCE[e]*256];
    const size_t sl = ((size_t)l*EVCAP + e)*256 + tid;
    float4 Rs = feS[sl], Re = feE[sl];
    const float inv = evInv[e];
    float4 fe;
    fe.x = ((Oe.x+Re.x)-(Os.x+Rs.x))*inv;
    fe.y = ((Oe.y+Re.y)-(Os.y+Rs.y))*inv;
    fe.z = ((Oe.z+Re.z)-(Os.z+Rs.z))*inv;
    fe.w = ((Oe.w+Re.w)-(Os.w+Rs.w))*inv;
    feE[sl] = fe;
    E.x+=fe.x; E.y+=fe.y; E.z+=fe.z; E.w+=fe.w;
  }
  S_evP[((size_t)l*EGRP + g)*256 + tid] = E;
}

// ---------------------------------------------------------------------------
// Kernel DS2: blocks [0,256): nb (from S_allB+S_evP sums) + excess partials;
// blocks [256,512): bank-score partials. No atomics.
// ---------------------------------------------------------------------------
__global__ __launch_bounds__(256) void kDS2(
    const float4* __restrict__ feE, const int* __restrict__ meta,
    const float4* __restrict__ S_allB, const float4* __restrict__ S_evP,
    const float4* __restrict__ baseline4,
    const float4* __restrict__ bank_ev4, const int* __restrict__ bank_step,
    const int* __restrict__ csptr,
    float4* __restrict__ out4, float4* __restrict__ S_exP,
    float4* __restrict__ SscoreP, int nonk)
{
  const int tid = threadIdx.x;
  if(blockIdx.x < 256){
    const int l = blockIdx.x >> 5, ech = blockIdx.x & 31;
    float4 sa = {0,0,0,0};
    #pragma unroll
    for(int b=0;b<B_;++b){
      float4 t = S_allB[((size_t)(l*B_+b))*256 + tid];
      sa.x+=t.x; sa.y+=t.y; sa.z+=t.z; sa.w+=t.w;
    }
    float4 se = {0,0,0,0};
    for(int g0=0; g0<EGRP; g0+=8){
      float4 t[8];
      #pragma unroll
      for(int j=0;j<8;++j) t[j] = S_evP[((size_t)l*EGRP + g0+j)*256 + tid];
      #pragma unroll
      for(int j=0;j<8;++j){ se.x+=t[j].x; se.y+=t[j].y; se.z+=t[j].z; se.w+=t[j].w; }
    }
    const float inv_nonk = 1.0f/(float)nonk;
    const float4 bl = baseline4[(size_t)l*256 + tid];
    float4 nb;
    nb.x = 0.99f*bl.x + 0.01f*((sa.x-se.x)*inv_nonk);
    nb.y = 0.99f*bl.y + 0.01f*((sa.y-se.y)*inv_nonk);
    nb.z = 0.99f*bl.z + 0.01f*((sa.z-se.z)*inv_nonk);
    nb.w = 0.99f*bl.w + 0.01f*((sa.w-se.w)*inv_nonk);
    if(ech == 0) out4[2048 + (size_t)l*256 + tid] = nb;
    const int nev = meta[8];
    const int per = (nev + 31) >> 5;
    const int e0 = ech*per;
    int e1 = e0 + per; if(e1 > nev) e1 = nev;
    float4 acc = {0,0,0,0};
    for(int e=e0;e<e1;++e){
      float4 fe = feE[((size_t)l*EVCAP + e)*256 + tid];
      acc.x += fmaxf(fe.x - nb.x, 0.f);
      acc.y += fmaxf(fe.y - nb.y, 0.f);
      acc.z += fmaxf(fe.z - nb.z, 0.f);
      acc.w += fmaxf(fe.w - nb.w, 0.f);
    }
    S_exP[((size_t)l*32 + ech)*256 + tid] = acc;
  } else {
    const int bx = blockIdx.x - 256;
    const int l = bx >> 5, sch = bx & 31;
    const int scount = TTL_/32;   // 32
    const int s0 = sch*scount;
    __shared__ float wl[TTL_/32];
    const int cs = csptr[0];
    if(tid < scount){
      int bs = bank_step[l*TTL_ + s0 + tid];
      float wgt = 0.f;
      if(bs >= 0){
        int a = cs - bs; if(a < 0) a = 0;
        wgt = exp2f(-(float)a * (1.0f/256.0f));
      }
      wl[tid] = wgt;
    }
    __syncthreads();
    float4 acc = {0,0,0,0};
    const float4* bp = bank_ev4 + ((size_t)l*TTL_ + s0)*256 + tid;
    #pragma unroll 8
    for(int j=0;j<scount;++j){
      float4 v = bp[(size_t)j*256];
      const float wv = wl[j];
      acc.x = fmaf(wv, v.x, acc.x); acc.y = fmaf(wv, v.y, acc.y);
      acc.z = fmaf(wv, v.z, acc.z); acc.w = fmaf(wv, v.w, acc.w);
    }
    SscoreP[((size_t)l*32 + sch)*256 + tid] = acc;
  }
}

// ---------------------------------------------------------------------------
// Kernel E: sum partials; evidence -> out[0], score -> out[2]. grid = L_.
// ---------------------------------------------------------------------------
__global__ __launch_bounds__(256) void kE(
    const float4* __restrict__ S_exP, const float4* __restrict__ SscoreP,
    const int* __restrict__ bank_step, const int* __restrict__ csptr,
    float4* __restrict__ out4, float kf)
{
  const int l = blockIdx.x;
  const int tid = threadIdx.x;
  __shared__ float red[256];
  const int cs = csptr[0];
  float wacc = 0.f;
  for(int s=tid; s<TTL_; s+=256){
    int bs = bank_step[l*TTL_+s];
    if(bs >= 0){
      int a = cs - bs; if(a<0) a=0;
      wacc += exp2f(-(float)a * (1.0f/256.0f));
    }
  }
  red[tid] = wacc;
  __syncthreads();
  for(int st=128; st>0; st>>=1){ if(tid<st) red[tid] += red[tid+st]; __syncthreads(); }
  const float wsum = red[0];

  float4 ex = {0,0,0,0}, ss = {0,0,0,0};
  for(int j0=0;j0<32;j0+=8){
    float4 a[8], b[8];
    #pragma unroll
    for(int j=0;j<8;++j){
      a[j] = S_exP[((size_t)l*32 + j0+j)*256 + tid];
      b[j] = SscoreP[((size_t)l*32 + j0+j)*256 + tid];
    }
    #pragma unroll
    for(int j=0;j<8;++j){
      ex.x+=a[j].x; ex.y+=a[j].y; ex.z+=a[j].z; ex.w+=a[j].w;
      ss.x+=b[j].x; ss.y+=b[j].y; ss.z+=b[j].z; ss.w+=b[j].w;
    }
  }
  const float invk = 1.0f/kf;
  float4 o0 = {ex.x*invk, ex.y*invk, ex.z*invk, ex.w*invk};
  out4[(size_t)l*256 + tid] = o0;
  float4 o2 = {0,0,0,0};
  if(wsum > 0.f){
    const float wm = fmaxf(wsum, 1e-12f);
    o2.x = ss.x/wm; o2.y = ss.y/wm; o2.z = ss.z/wm; o2.w = ss.w/wm;
  }
  out4[2*2048 + (size_t)l*256 + tid] = o2;
}

// ---------------------------------------------------------------------------
extern "C" void kernel_launch(void* const* d_in, const int* in_sizes, int n_in,
                              void* d_out, int out_size, void* d_ws, size_t ws_size,
                              hipStream_t stream)
{
  const float* pressure  = (const float*)d_in[0];
  const float* states    = (const float*)d_in[1];
  const float* bank_ev   = (const float*)d_in[2];
  const float* baseline  = (const float*)d_in[3];
  const int*   bank_step = (const int*)d_in[4];
  const int*   csptr     = (const int*)d_in[5];
  const int*   hptr      = (const int*)d_in[6];
  float* out = (float*)d_out;

  const int total = B_*T_;
  const int k = (int)llround(0.05 * (double)total);   // 410

  // workspace layout (bytes)
  char* ws = (char*)d_ws;
  float* w        = (float*)(ws + 0);          // 8 KB
  int*   meta     = (int*)(ws + 8192);         // 64 B
  int*   evB      = (int*)(ws + 16384);        // 2 KB
  int*   evCS     = (int*)(ws + 18432);        // 2 KB
  int*   evCE     = (int*)(ws + 20480);        // 2 KB
  float* evInv    = (float*)(ws + 22528);      // 2 KB
  unsigned short* markRowG = (unsigned short*)(ws + 24576);  // 8 KB
  unsigned short* markValG = (unsigned short*)(ws + 32768);  // 8 KB
  int*   mkStart  = (int*)(ws + 40960);        // 2 KB
  int*   mkCnt    = (int*)(ws + 43008);        // 2 KB
  float* S_allB   = (float*)(ws + 49152);      // 128 KB
  float* S_evP    = (float*)(ws + 1048576);    // 2 MB
  float* S_exP    = (float*)(ws + 3145728);    // 1 MB
  float* SscoreP  = (float*)(ws + 4194304);    // 1 MB
  float* chunkCS  = (float*)(ws + 8388608);    // 16 MB (becomes chunkOff)
  float* wAbuf    = (float*)(ws + 25165824);   // 16 MB
  float* feS      = (float*)(ws + 41943040);   // 16 MB
  float* feE      = (float*)(ws + 58720256);   // 16 MB

  const size_t need = 75497472ull;  // 72 MB
  if(ws_size < need) return;

  kA<<<1, 1024, 0, stream>>>(pressure, hptr, k, meta, w,
                             evB, evCS, evCE, evInv,
                             markRowG, markValG, mkStart, mkCnt);
  kSQ<<<L_*B_*NCQ, 256, 0, stream>>>(states, w, mkStart, mkCnt,
                                     markRowG, markValG,
                                     (float4*)chunkCS, (float4*)wAbuf,
                                     (float4*)feS, (float4*)feE);
  kScan<<<L_*B_*4, 256, 0, stream>>>(chunkCS, wAbuf, S_allB);
  kFE<<<L_*EGRP, 256, 0, stream>>>((const float4*)feS, (float4*)feE,
                                   (const float4*)chunkCS,
                                   evB, evCS, evCE, evInv, meta,
                                   (float4*)S_evP);
  kDS2<<<512, 256, 0, stream>>>((const float4*)feE, meta,
                                (const float4*)S_allB, (const float4*)S_evP,
                                (const float4*)baseline,
                                (const float4*)bank_ev, bank_step, csptr,
                                (float4*)out, (float4*)S_exP,
                                (float4*)SscoreP, total - k);
  kE<<<L_, 256, 0, stream>>>((const float4*)S_exP, (const float4*)SscoreP,
                             bank_step, csptr, (float4*)out, (float)k);
}